// Round 9
// baseline (415.057 us; speedup 1.0000x reference)
//
#include <hip/hip_runtime.h>
#include <math.h>

// LSTM B=8192,T=512,IN=3,H=32,OUT=2 fp32.
// R9 = R8 structure (8 batches/wave, 2-fold column replication, 1024 waves =
// 1/SIMD, lane pair n/n+8 splits the 8 units of each q-group 4/4) with:
//  - x@W_ih + bias moved back onto the MFMA via R3's verified K-packed AX/BX
//    frags (4th pass set) -> removes the per-lane xw/xbias fp32 constant
//    arrays (64 regs) whose rematerialization was inflating per-step VALU.
//  - preacts complete in acc: P = parity-select only (no adds).
//  - tail: 2 rcp/unit (c = N/D with one rcp of (1+Ef)(1+Ei)(1+Eg)).
// Zero LDS, zero barriers. Weights pre-scaled by -log2e (-2log2e for g).

namespace {
constexpr int   kT   = 512;
constexpr float kL2E = 1.44269504088896340736f;
}

typedef __bf16 bf16x8 __attribute__((ext_vector_type(8)));
typedef float  f32x4  __attribute__((ext_vector_type(4)));

union Frag {
    bf16x8 v;
    unsigned short u[8];
    unsigned int   d[4];
};

__device__ __forceinline__ unsigned short bf_rne(float f) {
    unsigned u = __float_as_uint(f);
    u += 0x7fffu + ((u >> 16) & 1u);
    return (unsigned short)(u >> 16);
}
__device__ __forceinline__ float bf_tof(unsigned short h) {
    return __uint_as_float((unsigned)h << 16);
}
__device__ __forceinline__ float fast_exp2(float v) { return __builtin_amdgcn_exp2f(v); }
__device__ __forceinline__ float fast_rcp(float v)  { return __builtin_amdgcn_rcpf(v); }
__device__ __forceinline__ unsigned pck(unsigned short a, unsigned short b) {
    return (unsigned)a | ((unsigned)b << 16);
}
// [lo16 = a.hi16, hi16 = b.hi16]  (bf16 truncation pack)
__device__ __forceinline__ unsigned pack_hi16(float a, float b) {
    return __builtin_amdgcn_perm(__float_as_uint(b), __float_as_uint(a), 0x07060302u);
}

#define MFMA16 __builtin_amdgcn_mfma_f32_16x16x32_bf16

extern "C" __global__ __launch_bounds__(64, 1)
void lstm_r9(const float* __restrict__ x,
             const float* __restrict__ W_ih,
             const float* __restrict__ W_hh,
             const float* __restrict__ b_ih,
             const float* __restrict__ b_hh,
             const float* __restrict__ W_fc,
             const float* __restrict__ b_fc,
             float* __restrict__ out) {
    const int  lane = threadIdx.x & 63;
    const int  n    = lane & 15;        // B/D column == A row
    const int  q    = lane >> 4;        // quad
    const int  pp   = (n >> 3) & 1;     // replica half: units +0..3 | +4..7
    const int  bat  = n & 7;            // batch within wave
    const int  b    = blockIdx.x * 8 + bat;
    const bool isP  = (pp != 0);
    const bool isQ0 = (q == 0);
    const bool isQ1 = (q == 1);
    const unsigned short ONE = 0x3F80;  // bf16 1.0

    // ---- A-frags: permuted scaled W_hh (hi/lo) ----
    // chunk cc (g=cc>>1, pc=cc&1): A row m holds W row
    // R = 32g + 8(m>>2) + 4pc + (m&3)  =>  D row 4q+r of chunk cc is
    // gate g, unit u = 8q + 4pc + r (verified R3/R5/R8).
    Frag Ah[8], Al[8], AX[8];
#pragma unroll
    for (int cc = 0; cc < 8; ++cc) {
        const int   g  = cc >> 1, pc = cc & 1;
        const float s  = (g == 2) ? -2.0f * kL2E : -kL2E;
        const int   R  = 32 * g + 8 * (n >> 2) + 4 * pc + (n & 3);
#pragma unroll
        for (int j = 0; j < 8; ++j) {
            const float w = W_hh[R * 32 + 8 * q + j] * s;
            const unsigned short hb = bf_rne(w);
            Ah[cc].u[j] = hb;
            Al[cc].u[j] = bf_rne(w - bf_tof(hb));
        }
        // AX (verified in R3): q0 k0-2 Wx_hi, k3-5 Wx_lo, k6-7 Wx_hi[0,1];
        //                      q1 k0 Wx_hi[2], k1 bias_hi, k2 bias_lo.
        float wh[3], wl[3];
#pragma unroll
        for (int j = 0; j < 3; ++j) {
            const float w = W_ih[R * 3 + j] * s;
            const unsigned short hb = bf_rne(w);
            wh[j] = bf_tof(hb);
            wl[j] = w - wh[j];
        }
        const float bias = (b_ih[R] + b_hh[R]) * s;
        const unsigned short bh = bf_rne(bias);
#pragma unroll
        for (int j = 0; j < 8; ++j) AX[cc].u[j] = 0;
        if (isQ0) {
            AX[cc].u[0] = bf_rne(wh[0]); AX[cc].u[1] = bf_rne(wh[1]); AX[cc].u[2] = bf_rne(wh[2]);
            AX[cc].u[3] = bf_rne(wl[0]); AX[cc].u[4] = bf_rne(wl[1]); AX[cc].u[5] = bf_rne(wl[2]);
            AX[cc].u[6] = bf_rne(wh[0]); AX[cc].u[7] = bf_rne(wh[1]);
        } else if (isQ1) {
            AX[cc].u[0] = bf_rne(wh[2]);
            AX[cc].u[1] = bh;
            AX[cc].u[2] = bf_rne(bias - bf_tof(bh));
        }
    }

    const float* xb = x + (size_t)b * kT * 3;

    const int u0 = 8 * q + 4 * pp;
    float cst[4]   = {0.f, 0.f, 0.f, 0.f};
    float hfull[4] = {0.f, 0.f, 0.f, 0.f};
    Frag Bh, Bl, BX;
#pragma unroll
    for (int j = 0; j < 4; ++j) { Bh.d[j] = 0; Bl.d[j] = 0; }

    // BX builder (verified in R3): q0 k = [xh0,xh1,xh2, xh0,xh1,xh2, xl0,xl1],
    //                              q1 k = [xl2, 1, 1, 0...], q2/q3 = 0.
    auto buildBX = [&](float x0, float x1, float x2) {
        const unsigned short xh0 = bf_rne(x0), xh1 = bf_rne(x1), xh2 = bf_rne(x2);
        const unsigned short xl0 = bf_rne(x0 - bf_tof(xh0));
        const unsigned short xl1 = bf_rne(x1 - bf_tof(xh1));
        const unsigned short xl2 = bf_rne(x2 - bf_tof(xh2));
        const unsigned q0d0 = pck(xh0, xh1), q0d1 = pck(xh2, xh0);
        const unsigned q0d2 = pck(xh1, xh2), q0d3 = pck(xl0, xl1);
        const unsigned q1d0 = pck(xl2, ONE), q1d1 = (unsigned)ONE;
        BX.d[0] = isQ0 ? q0d0 : (isQ1 ? q1d0 : 0u);
        BX.d[1] = isQ0 ? q0d1 : (isQ1 ? q1d1 : 0u);
        BX.d[2] = isQ0 ? q0d2 : 0u;
        BX.d[3] = isQ0 ? q0d3 : 0u;
    };
    buildBX(xb[0], xb[1], xb[2]);

    for (int t = 0; t < kT; ++t) {
        // ---- 32 MFMA: x-pass, then h hi/lo passes (8 independent chains) ----
        f32x4 acc[8];
        const f32x4 z = {0.f, 0.f, 0.f, 0.f};
#pragma unroll
        for (int cc = 0; cc < 8; ++cc) acc[cc] = MFMA16(AX[cc].v, BX.v, z, 0, 0, 0);
#pragma unroll
        for (int cc = 0; cc < 8; ++cc) acc[cc] = MFMA16(Ah[cc].v, Bh.v, acc[cc], 0, 0, 0);
#pragma unroll
        for (int cc = 0; cc < 8; ++cc) acc[cc] = MFMA16(Al[cc].v, Bh.v, acc[cc], 0, 0, 0);
#pragma unroll
        for (int cc = 0; cc < 8; ++cc) acc[cc] = MFMA16(Ah[cc].v, Bl.v, acc[cc], 0, 0, 0);

        // prefetch next x (fills MFMA shadow)
        const int tn = (t + 1 < kT) ? t + 1 : t;
        const float xn0 = xb[tn * 3 + 0];
        const float xn1 = xb[tn * 3 + 1];
        const float xn2 = xb[tn * 3 + 2];

        // ---- c/h update for my 4 units: P = parity-select(acc) only ----
        float hv[4];
#pragma unroll
        for (int r = 0; r < 4; ++r) {
            const float P0 = isP ? acc[1][r] : acc[0][r];
            const float P1 = isP ? acc[3][r] : acc[2][r];
            const float P2 = isP ? acc[5][r] : acc[4][r];
            const float P3 = isP ? acc[7][r] : acc[6][r];
            const float Ei = fast_exp2(P0);
            const float Ef = fast_exp2(P1);
            const float Eg = fast_exp2(P2);
            const float Eo = fast_exp2(P3);
            // c = [c*(1+Ei)(1+Eg) + (1-Eg)(1+Ef)] / [(1+Ef)(1+Ei)(1+Eg)]
            const float a  = 1.0f + Ei;
            const float bb = 1.0f + Ef;
            const float g1 = 1.0f + Eg;
            const float gm = 1.0f - Eg;
            const float ag = a * g1;
            const float N  = fmaf(cst[r], ag, gm * bb);
            const float c  = N * fast_rcp(bb * ag);
            cst[r] = c;
            float Ec = fast_exp2(c * (-2.0f * kL2E));
            Ec = fminf(Ec, 1e30f);                     // overflow guard
            const float h = (1.0f - Ec) * fast_rcp((1.0f + Eo) * (1.0f + Ec));
            hfull[r] = h;
            hv[r] = h;
        }

        // ---- hi/lo packing: truncate-high via v_perm, residual -> lo ----
        const unsigned hh01 = pack_hi16(hv[0], hv[1]);
        const unsigned hh23 = pack_hi16(hv[2], hv[3]);
        const float l0 = hv[0] - __uint_as_float(__float_as_uint(hv[0]) & 0xFFFF0000u);
        const float l1 = hv[1] - __uint_as_float(__float_as_uint(hv[1]) & 0xFFFF0000u);
        const float l2 = hv[2] - __uint_as_float(__float_as_uint(hv[2]) & 0xFFFF0000u);
        const float l3 = hv[3] - __uint_as_float(__float_as_uint(hv[3]) & 0xFFFF0000u);
        const unsigned hl01 = pack_hi16(l0, l1);
        const unsigned hl23 = pack_hi16(l2, l3);

        // ---- partner exchange (lane^8) + B assembly ----
        const unsigned ohh01 = __shfl_xor(hh01, 8, 64);
        const unsigned ohh23 = __shfl_xor(hh23, 8, 64);
        const unsigned ohl01 = __shfl_xor(hl01, 8, 64);
        const unsigned ohl23 = __shfl_xor(hl23, 8, 64);
        Bh.d[0] = isP ? ohh01 : hh01;
        Bh.d[1] = isP ? ohh23 : hh23;
        Bh.d[2] = isP ? hh01 : ohh01;
        Bh.d[3] = isP ? hh23 : ohh23;
        Bl.d[0] = isP ? ohl01 : hl01;
        Bl.d[1] = isP ? ohl23 : hl23;
        Bl.d[2] = isP ? hl01 : ohl01;
        Bl.d[3] = isP ? hl23 : ohl23;

        buildBX(xn0, xn1, xn2);
    }

    // ---- epilogue: out[b][o] = sum_u h_u W_fc[o][u] + b_fc[o] ----
    float s0 = 0.f, s1 = 0.f;
#pragma unroll
    for (int r = 0; r < 4; ++r) {
        const int u = u0 + r;
        s0 = fmaf(hfull[r], W_fc[u], s0);
        s1 = fmaf(hfull[r], W_fc[32 + u], s1);
    }
    s0 += __shfl_xor(s0, 8, 64);  s1 += __shfl_xor(s1, 8, 64);
    s0 += __shfl_xor(s0, 16, 64); s1 += __shfl_xor(s1, 16, 64);
    s0 += __shfl_xor(s0, 32, 64); s1 += __shfl_xor(s1, 32, 64);
    if (lane < 8) {
        out[(size_t)b * 2 + 0] = s0 + b_fc[0];
        out[(size_t)b * 2 + 1] = s1 + b_fc[1];
    }
}

extern "C" void kernel_launch(void* const* d_in, const int* in_sizes, int n_in,
                              void* d_out, int out_size, void* d_ws, size_t ws_size,
                              hipStream_t stream) {
    const float* x    = (const float*)d_in[0];
    const float* W_ih = (const float*)d_in[1];
    const float* W_hh = (const float*)d_in[2];
    const float* b_ih = (const float*)d_in[3];
    const float* b_hh = (const float*)d_in[4];
    const float* W_fc = (const float*)d_in[5];
    const float* b_fc = (const float*)d_in[6];
    float* out = (float*)d_out;

    const int batch = in_sizes[0] / (kT * 3);   // 8192
    dim3 grid(batch / 8);                       // 1024 blocks, 1 wave each
    dim3 block(64);                             // -> 1 wave per SIMD, all SIMDs
    hipLaunchKernelGGL(lstm_r9, grid, block, 0, stream,
                       x, W_ih, W_hh, b_ih, b_hh, W_fc, b_fc, out);
}